// Round 22
// baseline (256.321 us; speedup 1.0000x reference)
//
#include <hip/hip_runtime.h>
#include <math.h>

// Problem constants
#define B_   4096
#define N_   64
#define SS_  5
#define I_   7
#define H_   256
#define M1_  512
#define M2_  512
#define A_   81

typedef _Float16 f16;
typedef f16   f16x8 __attribute__((ext_vector_type(8)));
typedef float f32x4 __attribute__((ext_vector_type(4)));
typedef int   i32x4 __attribute__((ext_vector_type(4)));

__device__ __forceinline__ float rcp_(float x) { return __builtin_amdgcn_rcpf(x); }
__device__ __forceinline__ float ex2_(float x) { return __builtin_amdgcn_exp2f(x); }

// ---------------------------------------------------------------------------
// Kernel 0: pack weights. LSTM scales now carry the exp2-domain factor:
// gates i,f,o: -log2e; cell gate g: +2*log2e — folded into BOTH scd and the
// Wxk rows (incl. the j=7 bias slot). The lstm epilogue then uses native
// v_exp_f32 with no per-gate multiply. MLP packs unchanged.
// ---------------------------------------------------------------------------
__global__ __launch_bounds__(1024) void pack_weights(
    const float* __restrict__ W_ih,
    const float* __restrict__ W_hh,
    const float* __restrict__ b_ih,
    const float* __restrict__ b_hh,
    const float* __restrict__ W1,
    const float* __restrict__ W2,
    const float* __restrict__ Wv,
    signed char* __restrict__ Wq2,
    f16* __restrict__ Wxk,
    float* __restrict__ scd,
    f16* __restrict__ Wp1,
    f16* __restrict__ Wp2,
    f16* __restrict__ Wpv) {
  const int gtid = blockIdx.x * 1024 + threadIdx.x;

  if (gtid < 65536) {                   // --- LSTM pack ---
    const int p    = gtid >> 6;
    const int lane = gtid & 63;
    const int w16 = p >> 6, r = p & 63, g = r >> 4, uu = r & 15;
    const int row = g * H_ + w16 * 16 + uu;
    const float fac = (g == 2) ? 2.8853900817779268f : -1.4426950408889634f;

    const float4 v4 = *(const float4*)(W_hh + row * H_ + lane * 4);
    float mx = fmaxf(fmaxf(fabsf(v4.x), fabsf(v4.y)),
                     fmaxf(fabsf(v4.z), fabsf(v4.w)));
    #pragma unroll
    for (int off = 32; off; off >>= 1)
      mx = fmaxf(mx, __shfl_xor(mx, off));
    mx = fmaxf(mx, 1e-12f);
    const float is = 127.f / mx;

    int b0i = (int)rintf(v4.x * is), b1i = (int)rintf(v4.y * is);
    int b2i = (int)rintf(v4.z * is), b3i = (int)rintf(v4.w * is);
    b0i = max(-127, min(127, b0i)); b1i = max(-127, min(127, b1i));
    b2i = max(-127, min(127, b2i)); b3i = max(-127, min(127, b3i));
    const unsigned int packed = (b0i & 0xff) | ((b1i & 0xff) << 8) |
                                ((b2i & 0xff) << 16) | ((b3i & 0xff) << 24);
    const int k    = lane * 4;
    const int kt2  = k >> 6;
    const int kk   = k & 63;
    *(unsigned int*)(Wq2 + kt2 * 65536 + p * 64 + kk) = packed;

    if (lane < 8) {
      float v;
      if (lane < I_)      v = W_ih[row * I_ + lane];
      else                v = b_ih[row] + b_hh[row];   // bias in j=7
      Wxk[p * 8 + lane] = (f16)(v * fac);
    }
    if (lane == 9)  scd[p] = mx * (1.f / 16129.f) * fac;
  }

  // --- MLP packs ---
  if (gtid < 288 * 512) {               // W1 (Kpad 288, NT 32)
    const int k = gtid >> 9, n = gtid & 511;
    const int kt = k >> 5, lg = (k >> 3) & 3, j = k & 7;
    const int nt = n >> 4, l15 = n & 15;
    const float v = (k < 261) ? W1[k * 512 + n] : 0.f;
    Wp1[(((kt * 32 + nt) * 16 + l15) * 4 + lg) * 8 + j] = (f16)v;
  }
  if (gtid < 512 * 512) {               // W2 (K 512, NT 32)
    const int k = gtid >> 9, n = gtid & 511;
    const int kt = k >> 5, lg = (k >> 3) & 3, j = k & 7;
    const int nt = n >> 4, l15 = n & 15;
    Wp2[(((kt * 32 + nt) * 16 + l15) * 4 + lg) * 8 + j] = (f16)W2[k * 512 + n];
  }
  if (gtid < 512 * 96) {                // Wv (K 512, NT 6, n pad 96)
    const int k = gtid / 96, n = gtid - k * 96;
    const int kt = k >> 5, lg = (k >> 3) & 3, j = k & 7;
    const int nt = n >> 4, l15 = n & 15;
    const float v = (n < A_) ? Wv[k * A_ + n] : 0.f;
    Wpv[(((kt * 6 + nt) * 16 + l15) * 4 + lg) * 8 + j] = (f16)v;
  }
}

// ---------------------------------------------------------------------------
// Kernel 1: distance + stable descending rank-sort + gather (unchanged).
// ---------------------------------------------------------------------------
__global__ void sort_gather(const float* __restrict__ state,
                            f16* __restrict__ xbuf,
                            float* __restrict__ selfbuf) {
  const int b = blockIdx.x;
  const int e = threadIdx.x;                 // 0..63, one wave
  const float* row = state + ((size_t)b * N_ + e) * 12;
  const float4* r4 = (const float4*)row;
  const float4 v0 = r4[0], v1 = r4[1], v2 = r4[2];
  float s[12];
  s[0]=v0.x; s[1]=v0.y; s[2]=v0.z;  s[3]=v0.w;
  s[4]=v1.x; s[5]=v1.y; s[6]=v1.z;  s[7]=v1.w;
  s[8]=v2.x; s[9]=v2.y; s[10]=v2.z; s[11]=v2.w;

  const float s5 = s[5], s6 = s[6];
  const float d = (s5 != 0.f && s6 != 0.f) ? sqrtf(s5 * s5 + s6 * s6) : INFINITY;

  __shared__ float dd[64];
  dd[e] = d;
  __syncthreads();

  int rank = 0;
  #pragma unroll
  for (int j = 0; j < 64; ++j) {
    const float dj = dd[j];
    rank += (dj > d || (dj == d && j < e)) ? 1 : 0;
  }

  f16* xo = xbuf + (((size_t)(b >> 4) * 64 + rank) * 16 + (b & 15)) * 8;
  #pragma unroll
  for (int f = 0; f < I_; ++f) xo[f] = (f16)s[SS_ + f];
  xo[7] = (f16)1.f;                     // bias-fold slot

  if (e == 0) {
    #pragma unroll
    for (int i = 0; i < SS_; ++i) selfbuf[b * SS_ + i] = s[i];
  }
}

// ---------------------------------------------------------------------------
// Kernel 2: i8 K=64 MFMA LSTM. 256 blocks x 1024 threads (16 waves,
// 4/SIMD), 16 batches/block. All W_hh in 64 VGPRs; Wx fragments now also
// register-hoisted (laundering removed — 16 more regs, within the 128
// tier). Gates arrive in the exp2 domain (scales carry ±log2e), so the
// epilogue uses native v_exp with no per-gate multiply. hq conflict-free
// dbuf; xall preloaded. LDS: Bx 16384 + hq 8192 + xall 16384 = 40960 B.
// ---------------------------------------------------------------------------
__global__ __attribute__((amdgpu_flat_work_group_size(1024, 1024)))
void lstm_kernel(
    const f16* __restrict__ xbuf,       // [256][64][16][8]
    const signed char* __restrict__ Wq2,// [4][1024][64] i8
    const f16* __restrict__ Wxk,        // [1024][8] (j=7 bias, exp2-scaled)
    const float* __restrict__ scd,      // [1024]  mx/127^2 * gate factor
    float* __restrict__ hnbuf) {        // [B][256] fp32
  const int tid = threadIdx.x;
  const int l   = tid & 63;
  const int w   = tid >> 6;             // wave 0..15
  const int l15 = l & 15;
  const int lg  = l >> 4;               // 0..3
  const int b0  = blockIdx.x << 4;      // 16 batches per block

  extern __shared__ char smem[];
  f16*   Bx_s  = (f16*)smem;                        // 16384 B
  signed char* hq_s = (signed char*)(smem + 16384); //  8192 B [2][16][16][16]
  f16*   xall  = (f16*)(smem + 24576);              // 16384 B [64][16][8]

  {
    const f16x8* sx = (const f16x8*)Wxk;
    f16x8* dx = (f16x8*)Bx_s;
    for (int i = tid; i < 1024; i += 1024) dx[i] = sx[i];
    const f16x8* sa = (const f16x8*)(xbuf + (size_t)blockIdx.x * 8192);
    f16x8* da = (f16x8*)xall;
    for (int i = tid; i < 1024; i += 1024) da[i] = sa[i];
    for (int i = tid; i < 2048; i += 1024) ((int*)hq_s)[i] = 0;
  }

  // per-lane dequant scales: gates g of units u = w*16 + lg*4 + e
  float scv[4][4];
  #pragma unroll
  for (int g = 0; g < 4; ++g)
    #pragma unroll
    for (int e = 0; e < 4; ++e)
      scv[g][e] = scd[w * 64 + g * 16 + lg * 4 + e];

  const int SB  = w * 4096 + l15 * 64 + lg * 16;  // W A-frag lane base
  const int BXB = w * 1024 + l15 * 16;            // Wx A-frag base (+g*256)
  const int u0  = w * 16 + lg * 4;                // first of 4 owned units
  const int HW  = w * 256 + l15 * 16 + lg * 4;    // hq write (+buf*4096)
  const int HR  = l * 16;                         // hq read (+buf*4096+kt2*1024)

  // ALL W_hh fragments -> registers, loop-invariant (64 VGPRs)
  i32x4 Bq[4][4];
  #pragma unroll
  for (int kt2 = 0; kt2 < 4; ++kt2)
    #pragma unroll
    for (int g = 0; g < 4; ++g)
      Bq[kt2][g] = *(const i32x4*)(Wq2 + kt2 * 65536 + g * 1024 + SB);

  float c_[4] = {0.f, 0.f, 0.f, 0.f};

  __syncthreads();

  // Wx fragments -> registers (16 VGPRs, hoisted; no laundering)
  f16x8 Wxv[4];
  #pragma unroll
  for (int g = 0; g < 4; ++g)
    Wxv[g] = *(const f16x8*)((const char*)Bx_s + BXB + g * 256);

  #pragma unroll 1
  for (int t = 0; t < 64; ++t) {
    const int hrb = HR + ((t & 1) * 4096);

    // x B-fragment: col=batch=l15, k=lg*8+j valid only for lg==0
    f16x8 bx = {(f16)0.f,(f16)0.f,(f16)0.f,(f16)0.f,
                (f16)0.f,(f16)0.f,(f16)0.f,(f16)0.f};
    if (lg == 0) bx = *(const f16x8*)&xall[t * 128 + l15 * 8];

    i32x4 acc[4];
    #pragma unroll
    for (int g = 0; g < 4; ++g) acc[g] = (i32x4){0, 0, 0, 0};

    // all 4 kt2: W (A) from registers, hq (B) from LDS (conflict-free)
    #pragma unroll
    for (int kt2 = 0; kt2 < 4; ++kt2) {
      const i32x4 Hf = *(const i32x4*)&hq_s[hrb + kt2 * 1024];
      #pragma unroll
      for (int g = 0; g < 4; ++g)
        acc[g] = __builtin_amdgcn_mfma_i32_16x16x64_i8(Bq[kt2][g], Hf, acc[g], 0, 0, 0);
    }

    // combine: facc = cvt(acc)*scv + (x@Wx + bias), all in exp2 domain
    f32x4 facc[4];
    #pragma unroll
    for (int g = 0; g < 4; ++g) {
      f32x4 accF = (f32x4){0.f, 0.f, 0.f, 0.f};
      accF = __builtin_amdgcn_mfma_f32_16x16x32_f16(Wxv[g], bx, accF, 0, 0, 0);
      #pragma unroll
      for (int e = 0; e < 4; ++e)
        facc[g][e] = (float)acc[g][e] * scv[g][e] + accF[e];
    }

    // gates in exp2 domain: yi,yf,yo = -x*log2e ; yg = 2x*log2e
    float hv[4];
    #pragma unroll
    for (int e = 0; e < 4; ++e) {
      const float si = rcp_(1.f + ex2_(facc[0][e]));
      const float sf = rcp_(1.f + ex2_(facc[1][e]));
      const float tg = 1.f - 2.f * rcp_(ex2_(facc[2][e]) + 1.f);
      const float so = rcp_(1.f + ex2_(facc[3][e]));
      const float cn = sf * c_[e] + si * tg;
      c_[e] = cn;
      const float tc = 1.f - 2.f * rcp_(ex2_(cn * 2.8853900817779268f) + 1.f);
      hv[e] = so * tc;
    }
    // magic-number i8 quantization (bit-identical to rintf(h*127))
    const unsigned mg0 = __float_as_uint(fmaf(hv[0], 127.f, 12582912.f));
    const unsigned mg1 = __float_as_uint(fmaf(hv[1], 127.f, 12582912.f));
    const unsigned mg2 = __float_as_uint(fmaf(hv[2], 127.f, 12582912.f));
    const unsigned mg3 = __float_as_uint(fmaf(hv[3], 127.f, 12582912.f));
    *(unsigned int*)(hq_s + ((t + 1) & 1) * 4096 + HW) =
        (mg0 & 255u) | ((mg1 & 255u) << 8) | ((mg2 & 255u) << 16) | (mg3 << 24);
    if (t == 63) {
      float4 hx = {hv[0], hv[1], hv[2], hv[3]};
      *(float4*)&hnbuf[(size_t)(b0 + l15) * H_ + u0] = hx;
    }
    __syncthreads();
  }
}

// ---------------------------------------------------------------------------
// Kernel 3: MFMA MLP (unchanged from R17 — ~12 us).
// ---------------------------------------------------------------------------
__global__ __launch_bounds__(512) void mlp_kernel(
    const float* __restrict__ selfb, const float* __restrict__ hnbuf,
    const f16* __restrict__ Wp1, const float* __restrict__ b1,
    const f16* __restrict__ Wp2, const float* __restrict__ b2,
    const f16* __restrict__ Wpv, const float* __restrict__ bv,
    float* __restrict__ out) {
  const int tid = threadIdx.x;
  const int l   = tid & 63;
  const int w   = tid >> 6;             // wave 0..7
  const int l15 = l & 15;
  const int lg  = l >> 4;
  const int b0  = blockIdx.x << 5;      // 32 batches per block

  extern __shared__ char smem[];
  f16* aA = (f16*)smem;                         // [32][296]
  f16* aB = (f16*)(smem + 18944);               // [32][520]
  f16* aC = (f16*)(smem + 18944 + 33280);       // [32][520]

  for (int i = tid; i < 32 * 296; i += 512) {
    const int r = i / 296, cc = i - r * 296;
    float v = 0.f;
    if (cc < SS_)        v = selfb[(b0 + r) * SS_ + cc];
    else if (cc < 261)   v = hnbuf[((size_t)(b0 + r)) * H_ + cc - SS_];
    aA[i] = (f16)v;
  }
  __syncthreads();

  f32x4 acc[2][4];

  { // ---- layer 1: Kpad=288 (9 kt), N=512
    #pragma unroll
    for (int mt = 0; mt < 2; ++mt)
      #pragma unroll
      for (int nt4 = 0; nt4 < 4; ++nt4) acc[mt][nt4] = (f32x4){0.f,0.f,0.f,0.f};
    for (int kt = 0; kt < 9; ++kt) {
      const f16x8 A0 = *(const f16x8*)&aA[(l15) * 296 + kt * 32 + lg * 8];
      const f16x8 A1 = *(const f16x8*)&aA[(16 + l15) * 296 + kt * 32 + lg * 8];
      #pragma unroll
      for (int nt4 = 0; nt4 < 4; ++nt4) {
        const int nt = w * 4 + nt4;
        const f16x8 Bv = *(const f16x8*)(Wp1 + (((kt * 32 + nt) * 16 + l15) * 4 + lg) * 8);
        acc[0][nt4] = __builtin_amdgcn_mfma_f32_16x16x32_f16(A0, Bv, acc[0][nt4], 0, 0, 0);
        acc[1][nt4] = __builtin_amdgcn_mfma_f32_16x16x32_f16(A1, Bv, acc[1][nt4], 0, 0, 0);
      }
    }
    #pragma unroll
    for (int nt4 = 0; nt4 < 4; ++nt4) {
      const int n = (w * 4 + nt4) * 16 + l15;
      const float bb = b1[n];
      #pragma unroll
      for (int mt = 0; mt < 2; ++mt)
        #pragma unroll
        for (int e = 0; e < 4; ++e) {
          const float v = fmaxf(acc[mt][nt4][e] + bb, 0.f);
          aB[(mt * 16 + lg * 4 + e) * 520 + n] = (f16)v;
        }
    }
  }
  __syncthreads();

  { // ---- layer 2: K=512 (16 kt), N=512
    #pragma unroll
    for (int mt = 0; mt < 2; ++mt)
      #pragma unroll
      for (int nt4 = 0; nt4 < 4; ++nt4) acc[mt][nt4] = (f32x4){0.f,0.f,0.f,0.f};
    for (int kt = 0; kt < 16; ++kt) {
      const f16x8 A0 = *(const f16x8*)&aB[(l15) * 520 + kt * 32 + lg * 8];
      const f16x8 A1 = *(const f16x8*)&aB[(16 + l15) * 520 + kt * 32 + lg * 8];
      #pragma unroll
      for (int nt4 = 0; nt4 < 4; ++nt4) {
        const int nt = w * 4 + nt4;
        const f16x8 Bv = *(const f16x8*)(Wp2 + (((kt * 32 + nt) * 16 + l15) * 4 + lg) * 8);
        acc[0][nt4] = __builtin_amdgcn_mfma_f32_16x16x32_f16(A0, Bv, acc[0][nt4], 0, 0, 0);
        acc[1][nt4] = __builtin_amdgcn_mfma_f32_16x16x32_f16(A1, Bv, acc[1][nt4], 0, 0, 0);
      }
    }
    #pragma unroll
    for (int nt4 = 0; nt4 < 4; ++nt4) {
      const int n = (w * 4 + nt4) * 16 + l15;
      const float bb = b2[n];
      #pragma unroll
      for (int mt = 0; mt < 2; ++mt)
        #pragma unroll
        for (int e = 0; e < 4; ++e) {
          const float v = fmaxf(acc[mt][nt4][e] + bb, 0.f);
          aC[(mt * 16 + lg * 4 + e) * 520 + n] = (f16)v;
        }
    }
  }
  __syncthreads();

  // ---- layer 3: K=512 (16 kt), N=81 pad 96 (6 tiles); waves 0..5
  if (w < 6) {
    const int n = w * 16 + l15;
    f32x4 acc3[2];
    acc3[0] = (f32x4){0.f,0.f,0.f,0.f};
    acc3[1] = (f32x4){0.f,0.f,0.f,0.f};
    for (int kt = 0; kt < 16; ++kt) {
      const f16x8 A0 = *(const f16x8*)&aC[(l15) * 520 + kt * 32 + lg * 8];
      const f16x8 A1 = *(const f16x8*)&aC[(16 + l15) * 520 + kt * 32 + lg * 8];
      const f16x8 Bv = *(const f16x8*)(Wpv + (((kt * 6 + w) * 16 + l15) * 4 + lg) * 8);
      acc3[0] = __builtin_amdgcn_mfma_f32_16x16x32_f16(A0, Bv, acc3[0], 0, 0, 0);
      acc3[1] = __builtin_amdgcn_mfma_f32_16x16x32_f16(A1, Bv, acc3[1], 0, 0, 0);
    }
    if (n < A_) {
      const float bb = bv[n];
      #pragma unroll
      for (int mt = 0; mt < 2; ++mt)
        #pragma unroll
        for (int e = 0; e < 4; ++e)
          out[(size_t)(b0 + mt * 16 + lg * 4 + e) * A_ + n] = acc3[mt][e] + bb;
    }
  }
}

// ---------------------------------------------------------------------------
extern "C" void kernel_launch(void* const* d_in, const int* in_sizes, int n_in,
                              void* d_out, int out_size, void* d_ws, size_t ws_size,
                              hipStream_t stream) {
  const float* state = (const float*)d_in[0];
  const float* W_ih  = (const float*)d_in[1];
  const float* W_hh  = (const float*)d_in[2];
  const float* b_ih  = (const float*)d_in[3];
  const float* b_hh  = (const float*)d_in[4];
  const float* W1    = (const float*)d_in[5];
  const float* b1    = (const float*)d_in[6];
  const float* W2    = (const float*)d_in[7];
  const float* b2    = (const float*)d_in[8];
  const float* Wv    = (const float*)d_in[9];
  const float* bv    = (const float*)d_in[10];
  float* out = (float*)d_out;

  // workspace layout (bytes, 16B-aligned); total ~9.7 MB
  char* ws = (char*)d_ws;
  signed char* Wq2  = (signed char*)(ws);          // 262144 B
  f16*   Wxk     = (f16*)(ws + 262144);            // 16384 B
  float* scd     = (float*)(ws + 278528);          // 4096 B
  f16*   xbuf    = (f16*)(ws + 282624);            // 4194304 B
  float* selfb   = (float*)(ws + 4476928);         // 81920 B
  float* hnbuf   = (float*)(ws + 4558848);         // 4194304 B
  f16*   Wp1     = (f16*)(ws + 8753152);           // 294912 B
  f16*   Wp2     = (f16*)(ws + 9048064);           // 524288 B
  f16*   Wpv     = (f16*)(ws + 9572352);           // 98304 B

  pack_weights<<<dim3(256), dim3(1024), 0, stream>>>(
      W_ih, W_hh, b_ih, b_hh, W1, W2, Wv,
      Wq2, Wxk, scd, Wp1, Wp2, Wpv);
  sort_gather<<<dim3(B_), dim3(64), 0, stream>>>(state, xbuf, selfb);
  lstm_kernel<<<dim3(B_ / 16), dim3(1024), 40960, stream>>>(xbuf, Wq2, Wxk,
                                                            scd, hnbuf);
  mlp_kernel<<<dim3(B_ / 32), dim3(512), 85504, stream>>>(selfb, hnbuf,
                                                          Wp1, b1, Wp2, b2,
                                                          Wpv, bv, out);
}

// Round 23
// 159.681 us; speedup vs baseline: 1.6052x; 1.6052x over previous
//
#include <hip/hip_runtime.h>
#include <math.h>

// Problem constants
#define B_   4096
#define N_   64
#define SS_  5
#define I_   7
#define H_   256
#define M1_  512
#define M2_  512
#define A_   81

typedef _Float16 f16;
typedef f16   f16x8 __attribute__((ext_vector_type(8)));
typedef float f32x4 __attribute__((ext_vector_type(4)));
typedef int   i32x4 __attribute__((ext_vector_type(4)));

__device__ __forceinline__ float rcp_(float x) { return __builtin_amdgcn_rcpf(x); }
__device__ __forceinline__ float ex2_(float x) { return __builtin_amdgcn_exp2f(x); }

// ---------------------------------------------------------------------------
// Kernel 0: pack weights. LSTM scales carry the exp2-domain factor:
// gates i,f,o: -log2e; cell gate g: +2*log2e — folded into BOTH scd and the
// Wxk rows (incl. the j=7 bias slot). MLP packs unchanged.
// ---------------------------------------------------------------------------
__global__ __launch_bounds__(1024) void pack_weights(
    const float* __restrict__ W_ih,
    const float* __restrict__ W_hh,
    const float* __restrict__ b_ih,
    const float* __restrict__ b_hh,
    const float* __restrict__ W1,
    const float* __restrict__ W2,
    const float* __restrict__ Wv,
    signed char* __restrict__ Wq2,
    f16* __restrict__ Wxk,
    float* __restrict__ scd,
    f16* __restrict__ Wp1,
    f16* __restrict__ Wp2,
    f16* __restrict__ Wpv) {
  const int gtid = blockIdx.x * 1024 + threadIdx.x;

  if (gtid < 65536) {                   // --- LSTM pack ---
    const int p    = gtid >> 6;
    const int lane = gtid & 63;
    const int w16 = p >> 6, r = p & 63, g = r >> 4, uu = r & 15;
    const int row = g * H_ + w16 * 16 + uu;
    const float fac = (g == 2) ? 2.8853900817779268f : -1.4426950408889634f;

    const float4 v4 = *(const float4*)(W_hh + row * H_ + lane * 4);
    float mx = fmaxf(fmaxf(fabsf(v4.x), fabsf(v4.y)),
                     fmaxf(fabsf(v4.z), fabsf(v4.w)));
    #pragma unroll
    for (int off = 32; off; off >>= 1)
      mx = fmaxf(mx, __shfl_xor(mx, off));
    mx = fmaxf(mx, 1e-12f);
    const float is = 127.f / mx;

    int b0i = (int)rintf(v4.x * is), b1i = (int)rintf(v4.y * is);
    int b2i = (int)rintf(v4.z * is), b3i = (int)rintf(v4.w * is);
    b0i = max(-127, min(127, b0i)); b1i = max(-127, min(127, b1i));
    b2i = max(-127, min(127, b2i)); b3i = max(-127, min(127, b3i));
    const unsigned int packed = (b0i & 0xff) | ((b1i & 0xff) << 8) |
                                ((b2i & 0xff) << 16) | ((b3i & 0xff) << 24);
    const int k    = lane * 4;
    const int kt2  = k >> 6;
    const int kk   = k & 63;
    *(unsigned int*)(Wq2 + kt2 * 65536 + p * 64 + kk) = packed;

    if (lane < 8) {
      float v;
      if (lane < I_)      v = W_ih[row * I_ + lane];
      else                v = b_ih[row] + b_hh[row];   // bias in j=7
      Wxk[p * 8 + lane] = (f16)(v * fac);
    }
    if (lane == 9)  scd[p] = mx * (1.f / 16129.f) * fac;
  }

  // --- MLP packs ---
  if (gtid < 288 * 512) {               // W1 (Kpad 288, NT 32)
    const int k = gtid >> 9, n = gtid & 511;
    const int kt = k >> 5, lg = (k >> 3) & 3, j = k & 7;
    const int nt = n >> 4, l15 = n & 15;
    const float v = (k < 261) ? W1[k * 512 + n] : 0.f;
    Wp1[(((kt * 32 + nt) * 16 + l15) * 4 + lg) * 8 + j] = (f16)v;
  }
  if (gtid < 512 * 512) {               // W2 (K 512, NT 32)
    const int k = gtid >> 9, n = gtid & 511;
    const int kt = k >> 5, lg = (k >> 3) & 3, j = k & 7;
    const int nt = n >> 4, l15 = n & 15;
    Wp2[(((kt * 32 + nt) * 16 + l15) * 4 + lg) * 8 + j] = (f16)W2[k * 512 + n];
  }
  if (gtid < 512 * 96) {                // Wv (K 512, NT 6, n pad 96)
    const int k = gtid / 96, n = gtid - k * 96;
    const int kt = k >> 5, lg = (k >> 3) & 3, j = k & 7;
    const int nt = n >> 4, l15 = n & 15;
    const float v = (n < A_) ? Wv[k * A_ + n] : 0.f;
    Wpv[(((kt * 6 + nt) * 16 + l15) * 4 + lg) * 8 + j] = (f16)v;
  }
}

// ---------------------------------------------------------------------------
// Kernel 1: distance + stable descending rank-sort + gather (unchanged).
// ---------------------------------------------------------------------------
__global__ void sort_gather(const float* __restrict__ state,
                            f16* __restrict__ xbuf,
                            float* __restrict__ selfbuf) {
  const int b = blockIdx.x;
  const int e = threadIdx.x;                 // 0..63, one wave
  const float* row = state + ((size_t)b * N_ + e) * 12;
  const float4* r4 = (const float4*)row;
  const float4 v0 = r4[0], v1 = r4[1], v2 = r4[2];
  float s[12];
  s[0]=v0.x; s[1]=v0.y; s[2]=v0.z;  s[3]=v0.w;
  s[4]=v1.x; s[5]=v1.y; s[6]=v1.z;  s[7]=v1.w;
  s[8]=v2.x; s[9]=v2.y; s[10]=v2.z; s[11]=v2.w;

  const float s5 = s[5], s6 = s[6];
  const float d = (s5 != 0.f && s6 != 0.f) ? sqrtf(s5 * s5 + s6 * s6) : INFINITY;

  __shared__ float dd[64];
  dd[e] = d;
  __syncthreads();

  int rank = 0;
  #pragma unroll
  for (int j = 0; j < 64; ++j) {
    const float dj = dd[j];
    rank += (dj > d || (dj == d && j < e)) ? 1 : 0;
  }

  f16* xo = xbuf + (((size_t)(b >> 4) * 64 + rank) * 16 + (b & 15)) * 8;
  #pragma unroll
  for (int f = 0; f < I_; ++f) xo[f] = (f16)s[SS_ + f];
  xo[7] = (f16)1.f;                     // bias-fold slot

  if (e == 0) {
    #pragma unroll
    for (int i = 0; i < SS_; ++i) selfbuf[b * SS_ + i] = s[i];
  }
}

// ---------------------------------------------------------------------------
// Kernel 2: i8 K=64 MFMA LSTM — R21 structure (z-laundering RESTORED; Wx
// fragments read in-loop through the laundered base: the one opaque anchor
// that keeps the allocator from sinking the 64 Bq weight regs, proven by
// R22's regression). exp2-domain gates on top (scales carry ±log2e).
// LDS: Bx 16384 + hq 8192 + xall 16384 = 40960 B.
// ---------------------------------------------------------------------------
__global__ __attribute__((amdgpu_flat_work_group_size(1024, 1024)))
void lstm_kernel(
    const f16* __restrict__ xbuf,       // [256][64][16][8]
    const signed char* __restrict__ Wq2,// [4][1024][64] i8
    const f16* __restrict__ Wxk,        // [1024][8] (j=7 bias, exp2-scaled)
    const float* __restrict__ scd,      // [1024]  mx/127^2 * gate factor
    float* __restrict__ hnbuf) {        // [B][256] fp32
  const int tid = threadIdx.x;
  const int l   = tid & 63;
  const int w   = tid >> 6;             // wave 0..15
  const int l15 = l & 15;
  const int lg  = l >> 4;               // 0..3
  const int b0  = blockIdx.x << 4;      // 16 batches per block

  extern __shared__ char smem[];
  f16*   Bx_s  = (f16*)smem;                        // 16384 B
  signed char* hq_s = (signed char*)(smem + 16384); //  8192 B [2][16][16][16]
  f16*   xall  = (f16*)(smem + 24576);              // 16384 B [64][16][8]

  {
    const f16x8* sx = (const f16x8*)Wxk;
    f16x8* dx = (f16x8*)Bx_s;
    for (int i = tid; i < 1024; i += 1024) dx[i] = sx[i];
    const f16x8* sa = (const f16x8*)(xbuf + (size_t)blockIdx.x * 8192);
    f16x8* da = (f16x8*)xall;
    for (int i = tid; i < 1024; i += 1024) da[i] = sa[i];
    for (int i = tid; i < 2048; i += 1024) ((int*)hq_s)[i] = 0;
  }

  // per-lane dequant scales: gates g of units u = w*16 + lg*4 + e
  float scv[4][4];
  #pragma unroll
  for (int g = 0; g < 4; ++g)
    #pragma unroll
    for (int e = 0; e < 4; ++e)
      scv[g][e] = scd[w * 64 + g * 16 + lg * 4 + e];

  const int SB  = w * 4096 + l15 * 64 + lg * 16;  // W A-frag lane base
  const int BXB = w * 1024 + l15 * 16;            // Wx A-frag base (+g*256)
  const int u0  = w * 16 + lg * 4;                // first of 4 owned units
  const int HW  = w * 256 + l15 * 16 + lg * 4;    // hq write (+buf*4096)
  const int HR  = l * 16;                         // hq read (+buf*4096+kt2*1024)

  // ALL W_hh fragments -> registers, loop-invariant (64 VGPRs)
  i32x4 Bq[4][4];
  #pragma unroll
  for (int kt2 = 0; kt2 < 4; ++kt2)
    #pragma unroll
    for (int g = 0; g < 4; ++g)
      Bq[kt2][g] = *(const i32x4*)(Wq2 + kt2 * 65536 + g * 1024 + SB);

  float c_[4] = {0.f, 0.f, 0.f, 0.f};

  __syncthreads();

  #pragma unroll 1
  for (int t = 0; t < 64; ++t) {
    int z = 0;
    asm volatile("" : "+v"(z));          // the opaque anchor (R22 lesson)
    const int hrb = HR + ((t & 1) * 4096);
    const int bxb = BXB + z;

    // x B-fragment: col=batch=l15, k=lg*8+j valid only for lg==0
    f16x8 bx = {(f16)0.f,(f16)0.f,(f16)0.f,(f16)0.f,
                (f16)0.f,(f16)0.f,(f16)0.f,(f16)0.f};
    if (lg == 0) bx = *(const f16x8*)&xall[t * 128 + l15 * 8];

    i32x4 acc[4];
    #pragma unroll
    for (int g = 0; g < 4; ++g) acc[g] = (i32x4){0, 0, 0, 0};

    // all 4 kt2: W (A) from registers, hq (B) from LDS (conflict-free)
    #pragma unroll
    for (int kt2 = 0; kt2 < 4; ++kt2) {
      const i32x4 Hf = *(const i32x4*)&hq_s[hrb + kt2 * 1024];
      #pragma unroll
      for (int g = 0; g < 4; ++g)
        acc[g] = __builtin_amdgcn_mfma_i32_16x16x64_i8(Bq[kt2][g], Hf, acc[g], 0, 0, 0);
    }

    // combine: facc = cvt(acc)*scv + (x@Wx + bias), all in exp2 domain
    f32x4 facc[4];
    #pragma unroll
    for (int g = 0; g < 4; ++g) {
      f32x4 accF = (f32x4){0.f, 0.f, 0.f, 0.f};
      const f16x8 Wxv = *(const f16x8*)((const char*)Bx_s + bxb + g * 256);
      accF = __builtin_amdgcn_mfma_f32_16x16x32_f16(Wxv, bx, accF, 0, 0, 0);
      #pragma unroll
      for (int e = 0; e < 4; ++e)
        facc[g][e] = (float)acc[g][e] * scv[g][e] + accF[e];
    }

    // gates in exp2 domain: yi,yf,yo = -x*log2e ; yg = 2x*log2e
    float hv[4];
    #pragma unroll
    for (int e = 0; e < 4; ++e) {
      const float si = rcp_(1.f + ex2_(facc[0][e]));
      const float sf = rcp_(1.f + ex2_(facc[1][e]));
      const float tg = 1.f - 2.f * rcp_(ex2_(facc[2][e]) + 1.f);
      const float so = rcp_(1.f + ex2_(facc[3][e]));
      const float cn = sf * c_[e] + si * tg;
      c_[e] = cn;
      const float tc = 1.f - 2.f * rcp_(ex2_(cn * 2.8853900817779268f) + 1.f);
      hv[e] = so * tc;
    }
    // magic-number i8 quantization (bit-identical to rintf(h*127))
    const unsigned mg0 = __float_as_uint(fmaf(hv[0], 127.f, 12582912.f));
    const unsigned mg1 = __float_as_uint(fmaf(hv[1], 127.f, 12582912.f));
    const unsigned mg2 = __float_as_uint(fmaf(hv[2], 127.f, 12582912.f));
    const unsigned mg3 = __float_as_uint(fmaf(hv[3], 127.f, 12582912.f));
    *(unsigned int*)(hq_s + ((t + 1) & 1) * 4096 + HW) =
        (mg0 & 255u) | ((mg1 & 255u) << 8) | ((mg2 & 255u) << 16) | (mg3 << 24);
    if (t == 63) {
      float4 hx = {hv[0], hv[1], hv[2], hv[3]};
      *(float4*)&hnbuf[(size_t)(b0 + l15) * H_ + u0] = hx;
    }
    __syncthreads();
  }
}

// ---------------------------------------------------------------------------
// Kernel 3: MFMA MLP (unchanged from R17 — ~12 us).
// ---------------------------------------------------------------------------
__global__ __launch_bounds__(512) void mlp_kernel(
    const float* __restrict__ selfb, const float* __restrict__ hnbuf,
    const f16* __restrict__ Wp1, const float* __restrict__ b1,
    const f16* __restrict__ Wp2, const float* __restrict__ b2,
    const f16* __restrict__ Wpv, const float* __restrict__ bv,
    float* __restrict__ out) {
  const int tid = threadIdx.x;
  const int l   = tid & 63;
  const int w   = tid >> 6;             // wave 0..7
  const int l15 = l & 15;
  const int lg  = l >> 4;
  const int b0  = blockIdx.x << 5;      // 32 batches per block

  extern __shared__ char smem[];
  f16* aA = (f16*)smem;                         // [32][296]
  f16* aB = (f16*)(smem + 18944);               // [32][520]
  f16* aC = (f16*)(smem + 18944 + 33280);       // [32][520]

  for (int i = tid; i < 32 * 296; i += 512) {
    const int r = i / 296, cc = i - r * 296;
    float v = 0.f;
    if (cc < SS_)        v = selfb[(b0 + r) * SS_ + cc];
    else if (cc < 261)   v = hnbuf[((size_t)(b0 + r)) * H_ + cc - SS_];
    aA[i] = (f16)v;
  }
  __syncthreads();

  f32x4 acc[2][4];

  { // ---- layer 1: Kpad=288 (9 kt), N=512
    #pragma unroll
    for (int mt = 0; mt < 2; ++mt)
      #pragma unroll
      for (int nt4 = 0; nt4 < 4; ++nt4) acc[mt][nt4] = (f32x4){0.f,0.f,0.f,0.f};
    for (int kt = 0; kt < 9; ++kt) {
      const f16x8 A0 = *(const f16x8*)&aA[(l15) * 296 + kt * 32 + lg * 8];
      const f16x8 A1 = *(const f16x8*)&aA[(16 + l15) * 296 + kt * 32 + lg * 8];
      #pragma unroll
      for (int nt4 = 0; nt4 < 4; ++nt4) {
        const int nt = w * 4 + nt4;
        const f16x8 Bv = *(const f16x8*)(Wp1 + (((kt * 32 + nt) * 16 + l15) * 4 + lg) * 8);
        acc[0][nt4] = __builtin_amdgcn_mfma_f32_16x16x32_f16(A0, Bv, acc[0][nt4], 0, 0, 0);
        acc[1][nt4] = __builtin_amdgcn_mfma_f32_16x16x32_f16(A1, Bv, acc[1][nt4], 0, 0, 0);
      }
    }
    #pragma unroll
    for (int nt4 = 0; nt4 < 4; ++nt4) {
      const int n = (w * 4 + nt4) * 16 + l15;
      const float bb = b1[n];
      #pragma unroll
      for (int mt = 0; mt < 2; ++mt)
        #pragma unroll
        for (int e = 0; e < 4; ++e) {
          const float v = fmaxf(acc[mt][nt4][e] + bb, 0.f);
          aB[(mt * 16 + lg * 4 + e) * 520 + n] = (f16)v;
        }
    }
  }
  __syncthreads();

  { // ---- layer 2: K=512 (16 kt), N=512
    #pragma unroll
    for (int mt = 0; mt < 2; ++mt)
      #pragma unroll
      for (int nt4 = 0; nt4 < 4; ++nt4) acc[mt][nt4] = (f32x4){0.f,0.f,0.f,0.f};
    for (int kt = 0; kt < 16; ++kt) {
      const f16x8 A0 = *(const f16x8*)&aB[(l15) * 520 + kt * 32 + lg * 8];
      const f16x8 A1 = *(const f16x8*)&aB[(16 + l15) * 520 + kt * 32 + lg * 8];
      #pragma unroll
      for (int nt4 = 0; nt4 < 4; ++nt4) {
        const int nt = w * 4 + nt4;
        const f16x8 Bv = *(const f16x8*)(Wp2 + (((kt * 32 + nt) * 16 + l15) * 4 + lg) * 8);
        acc[0][nt4] = __builtin_amdgcn_mfma_f32_16x16x32_f16(A0, Bv, acc[0][nt4], 0, 0, 0);
        acc[1][nt4] = __builtin_amdgcn_mfma_f32_16x16x32_f16(A1, Bv, acc[1][nt4], 0, 0, 0);
      }
    }
    #pragma unroll
    for (int nt4 = 0; nt4 < 4; ++nt4) {
      const int n = (w * 4 + nt4) * 16 + l15;
      const float bb = b2[n];
      #pragma unroll
      for (int mt = 0; mt < 2; ++mt)
        #pragma unroll
        for (int e = 0; e < 4; ++e) {
          const float v = fmaxf(acc[mt][nt4][e] + bb, 0.f);
          aC[(mt * 16 + lg * 4 + e) * 520 + n] = (f16)v;
        }
    }
  }
  __syncthreads();

  // ---- layer 3: K=512 (16 kt), N=81 pad 96 (6 tiles); waves 0..5
  if (w < 6) {
    const int n = w * 16 + l15;
    f32x4 acc3[2];
    acc3[0] = (f32x4){0.f,0.f,0.f,0.f};
    acc3[1] = (f32x4){0.f,0.f,0.f,0.f};
    for (int kt = 0; kt < 16; ++kt) {
      const f16x8 A0 = *(const f16x8*)&aC[(l15) * 520 + kt * 32 + lg * 8];
      const f16x8 A1 = *(const f16x8*)&aC[(16 + l15) * 520 + kt * 32 + lg * 8];
      const f16x8 Bv = *(const f16x8*)(Wpv + (((kt * 6 + w) * 16 + l15) * 4 + lg) * 8);
      acc3[0] = __builtin_amdgcn_mfma_f32_16x16x32_f16(A0, Bv, acc3[0], 0, 0, 0);
      acc3[1] = __builtin_amdgcn_mfma_f32_16x16x32_f16(A1, Bv, acc3[1], 0, 0, 0);
    }
    if (n < A_) {
      const float bb = bv[n];
      #pragma unroll
      for (int mt = 0; mt < 2; ++mt)
        #pragma unroll
        for (int e = 0; e < 4; ++e)
          out[(size_t)(b0 + mt * 16 + lg * 4 + e) * A_ + n] = acc3[mt][e] + bb;
    }
  }
}

// ---------------------------------------------------------------------------
extern "C" void kernel_launch(void* const* d_in, const int* in_sizes, int n_in,
                              void* d_out, int out_size, void* d_ws, size_t ws_size,
                              hipStream_t stream) {
  const float* state = (const float*)d_in[0];
  const float* W_ih  = (const float*)d_in[1];
  const float* W_hh  = (const float*)d_in[2];
  const float* b_ih  = (const float*)d_in[3];
  const float* b_hh  = (const float*)d_in[4];
  const float* W1    = (const float*)d_in[5];
  const float* b1    = (const float*)d_in[6];
  const float* W2    = (const float*)d_in[7];
  const float* b2    = (const float*)d_in[8];
  const float* Wv    = (const float*)d_in[9];
  const float* bv    = (const float*)d_in[10];
  float* out = (float*)d_out;

  // workspace layout (bytes, 16B-aligned); total ~9.7 MB
  char* ws = (char*)d_ws;
  signed char* Wq2  = (signed char*)(ws);          // 262144 B
  f16*   Wxk     = (f16*)(ws + 262144);            // 16384 B
  float* scd     = (float*)(ws + 278528);          // 4096 B
  f16*   xbuf    = (f16*)(ws + 282624);            // 4194304 B
  float* selfb   = (float*)(ws + 4476928);         // 81920 B
  float* hnbuf   = (float*)(ws + 4558848);         // 4194304 B
  f16*   Wp1     = (f16*)(ws + 8753152);           // 294912 B
  f16*   Wp2     = (f16*)(ws + 9048064);           // 524288 B
  f16*   Wpv     = (f16*)(ws + 9572352);           // 98304 B

  pack_weights<<<dim3(256), dim3(1024), 0, stream>>>(
      W_ih, W_hh, b_ih, b_hh, W1, W2, Wv,
      Wq2, Wxk, scd, Wp1, Wp2, Wpv);
  sort_gather<<<dim3(B_), dim3(64), 0, stream>>>(state, xbuf, selfb);
  lstm_kernel<<<dim3(B_ / 16), dim3(1024), 40960, stream>>>(xbuf, Wq2, Wxk,
                                                            scd, hnbuf);
  mlp_kernel<<<dim3(B_ / 32), dim3(512), 85504, stream>>>(selfb, hnbuf,
                                                          Wp1, b1, Wp2, b2,
                                                          Wpv, bv, out);
}